// Round 8
// baseline (27.996 us; speedup 1.0000x reference)
//
#include <hip/hip_runtime.h>

// LBP encoder: out[n,k,h,w] = sigmoid(img[n,0,clamp(h+dy_k),clamp(w+dx_k)] - img[n,0,h,w])
// Offsets k=0..7: (-1,-1),(-1,0),(-1,1),(0,-1),(0,1),(1,-1),(1,0),(1,1)
// Round 8: 4-col x 4-row tile per thread (vs 4x2) + nt stores + XCD swizzle.
//  - read amplification 2x -> 1.5x (6 halo rows per 4 output rows);
//  - half the waves: shorter launch ramp, half the address setup;
//  - stores stay fully dense (lane stride 16B, rr-loop over rows).

#define NH 512
#define NW 512
#define HWSZ (NH * NW)

typedef float fx4 __attribute__((ext_vector_type(4)));

__device__ __forceinline__ float fexp2(float x) {
#if __has_builtin(__builtin_amdgcn_exp2f)
    return __builtin_amdgcn_exp2f(x);
#else
    return __expf(x * 0.6931471805599453f);
#endif
}

__device__ __forceinline__ float frcp(float x) {
#if __has_builtin(__builtin_amdgcn_rcpf)
    return __builtin_amdgcn_rcpf(x);
#else
    return 1.0f / x;
#endif
}

__global__ __launch_bounds__(256) void lbp_kernel(const float* __restrict__ img,
                                                  float* __restrict__ out) {
    const float L2E = 1.4426950408889634f;

    // XCD-chunked swizzle: 1024 blocks, 8 XCDs, 128 blocks/XCD chunk (bijective).
    int bid = blockIdx.x;
    int wgid = ((bid & 7) << 7) + (bid >> 3);

    // 64 blocks per image; n provably uniform per wave.
    int n = wgid >> 6;
    int local = ((wgid & 63) << 8) | threadIdx.x;  // 0..16383 within image
    int w0 = (local & 127) << 2;                   // 128 groups of 4 cols
    int h0 = (local >> 7) << 2;                    // 128 strips of 4 rows

    const float* src = img + (size_t)n * HWSZ;
    int wl = (w0 > 0) ? w0 - 1 : 0;
    int wr = (w0 + 4 < NW) ? w0 + 4 : NW - 1;

    // Halo: rows h0-1 .. h0+4 (clamped), cols w0-1 .. w0+4 (clamped),
    // pre-scaled by log2(e) so sigmoid = sub + exp2 + add + rcp.
    float r[6][6];
#pragma unroll
    for (int i = 0; i < 6; ++i) {
        int row = h0 - 1 + i;
        row = (row < 0) ? 0 : ((row > NH - 1) ? NH - 1 : row);
        const float* rp = src + row * NW;
        fx4 m = *reinterpret_cast<const fx4*>(rp + w0);
        r[i][0] = rp[wl] * L2E;
        r[i][1] = m.x * L2E;
        r[i][2] = m.y * L2E;
        r[i][3] = m.z * L2E;
        r[i][4] = m.w * L2E;
        r[i][5] = rp[wr] * L2E;
    }

    int off = h0 * NW + w0;  // shared store offset (elements)

    // Row delta and column base (dx+1) for each of the 8 offsets.
    const int RI[8] = {0, 0, 0, 1, 1, 2, 2, 2};  // dy+1
    const int CI[8] = {0, 1, 2, 0, 2, 0, 1, 2};  // dx+1

#pragma unroll
    for (int k = 0; k < 8; ++k) {
        const int ri = RI[k], ci = CI[k];
        float* base = out + ((size_t)(n * 8 + k)) * HWSZ;  // wave-uniform -> SGPR
#pragma unroll
        for (int rr = 0; rr < 4; ++rr) {
            fx4 res;
#pragma unroll
            for (int i = 0; i < 4; ++i) {
                // sigmoid(nb - c) = 1 / (1 + 2^(cL - nbL))
                res[i] = frcp(1.0f + fexp2(r[rr + 1][i + 1] - r[rr + ri][i + ci]));
            }
            __builtin_nontemporal_store(res, reinterpret_cast<fx4*>(base + off + rr * NW));
        }
    }
}

extern "C" void kernel_launch(void* const* d_in, const int* in_sizes, int n_in,
                              void* d_out, int out_size, void* d_ws, size_t ws_size,
                              hipStream_t stream) {
    const float* img = (const float*)d_in[0];
    float* out = (float*)d_out;
    // 16 images * 64 blocks/image = 1024 blocks of 256 threads
    lbp_kernel<<<1024, 256, 0, stream>>>(img, out);
}

// Round 9
// 26.316 us; speedup vs baseline: 1.0638x; 1.0638x over previous
//
#include <hip/hip_runtime.h>

// LBP encoder: out[n,k,h,w] = sigmoid(img[n,0,clamp(h+dy_k),clamp(w+dx_k)] - img[n,0,h,w])
// Offsets k=0..7: (-1,-1),(-1,0),(-1,1),(0,-1),(0,1),(1,-1),(1,0),(1,1)
// Round 9: REVERT to round-7 best (26.83 us). Round-8's 4-row tile regressed
// (occupancy loss beat read-amplification savings in this write-dominated op).
// Final configuration:
//  - 4-col x 2-row tile/thread, 2048 blocks x 256 -> 8 waves/SIMD;
//  - sigmoid = sub + v_exp_f32 + add + v_rcp_f32 (halo pre-scaled by log2 e);
//  - dense 1KB nt dwordx4 stores (write-once output, no cache allocation);
//  - XCD-chunked swizzle: 4 whole images per XCD -> halo re-reads hit local L2.

#define NH 512
#define NW 512
#define HWSZ (NH * NW)

typedef float fx4 __attribute__((ext_vector_type(4)));

__device__ __forceinline__ float fexp2(float x) {
#if __has_builtin(__builtin_amdgcn_exp2f)
    return __builtin_amdgcn_exp2f(x);
#else
    return __expf(x * 0.6931471805599453f);
#endif
}

__device__ __forceinline__ float frcp(float x) {
#if __has_builtin(__builtin_amdgcn_rcpf)
    return __builtin_amdgcn_rcpf(x);
#else
    return 1.0f / x;
#endif
}

__global__ __launch_bounds__(256) void lbp_kernel(const float* __restrict__ img,
                                                  float* __restrict__ out) {
    const float L2E = 1.4426950408889634f;

    // XCD-chunked swizzle: 2048 blocks, 8 XCDs, 256 blocks/XCD chunk (bijective).
    int bid = blockIdx.x;
    int wgid = ((bid & 7) << 8) + (bid >> 3);

    // 128 work-ids per image; n provably uniform per wave.
    int n = wgid >> 7;
    int local = ((wgid & 127) << 8) | threadIdx.x;  // 0..32767 within image
    int w0 = (local & 127) << 2;                    // 128 groups of 4 cols
    int h0 = (local >> 7) << 1;                     // 256 strips of 2 rows

    const float* src = img + (size_t)n * HWSZ;
    int wl = (w0 > 0) ? w0 - 1 : 0;
    int wr = (w0 + 4 < NW) ? w0 + 4 : NW - 1;

    // Halo: rows h0-1 .. h0+2 (clamped), cols w0-1 .. w0+4 (clamped),
    // pre-scaled by log2(e) so sigmoid = sub + exp2 + add + rcp.
    float r[4][6];
#pragma unroll
    for (int i = 0; i < 4; ++i) {
        int row = h0 - 1 + i;
        row = (row < 0) ? 0 : ((row > NH - 1) ? NH - 1 : row);
        const float* rp = src + row * NW;
        fx4 m = *reinterpret_cast<const fx4*>(rp + w0);
        r[i][0] = rp[wl] * L2E;
        r[i][1] = m.x * L2E;
        r[i][2] = m.y * L2E;
        r[i][3] = m.z * L2E;
        r[i][4] = m.w * L2E;
        r[i][5] = rp[wr] * L2E;
    }

    int off = h0 * NW + w0;  // shared store offset (elements)

    // Row delta and column base (dx+1) for each of the 8 offsets.
    const int RI[8] = {0, 0, 0, 1, 1, 2, 2, 2};  // dy+1
    const int CI[8] = {0, 1, 2, 0, 2, 0, 1, 2};  // dx+1

#pragma unroll
    for (int k = 0; k < 8; ++k) {
        const int ri = RI[k], ci = CI[k];
        float* base = out + ((size_t)(n * 8 + k)) * HWSZ;  // wave-uniform -> SGPR
#pragma unroll
        for (int rr = 0; rr < 2; ++rr) {
            fx4 res;
#pragma unroll
            for (int i = 0; i < 4; ++i) {
                // sigmoid(nb - c) = 1 / (1 + 2^(cL - nbL))
                res[i] = frcp(1.0f + fexp2(r[rr + 1][i + 1] - r[rr + ri][i + ci]));
            }
            __builtin_nontemporal_store(res, reinterpret_cast<fx4*>(base + off + rr * NW));
        }
    }
}

extern "C" void kernel_launch(void* const* d_in, const int* in_sizes, int n_in,
                              void* d_out, int out_size, void* d_ws, size_t ws_size,
                              hipStream_t stream) {
    const float* img = (const float*)d_in[0];
    float* out = (float*)d_out;
    // 16 images * 128 work-ids/image = 2048 blocks of 256 threads
    lbp_kernel<<<2048, 256, 0, stream>>>(img, out);
}